// Round 2
// baseline (1191.583 us; speedup 1.0000x reference)
//
#include <hip/hip_runtime.h>
#include <math.h>

#define NIMG 16
#define FH 1080
#define FW 1920
#define HHh 540
#define HWw 960
#define FHW (FH*FW)        // 2073600
#define TMPW (HHh*FW)      // 1036800
#define HHW (HHh*HWw)      // 518400
#define NG 9801
#define NSLOT 32

struct GW { float w[7]; };

__device__ const float FR[36][2] = {
 {0.338f, 10.f}, {0.017204f, 0.806612f}, {0.236f, 1.642f}, {-0.123884f, 0.20293f},
 {0.000155f, 0.712298f}, {0.001122f, 0.470257f}, {0.244f, 1.641f}, {-0.123586f, 0.179083f},
 {0.000152f, 0.710456f}, {0.000975f, 0.470984f}, {0.249f, 1.555f}, {-0.135687f, 0.100858f},
 {0.000174f, 0.684173f}, {0.000913f, 0.534174f}, {0.258f, 1.561f}, {-0.143408f, 0.100486f},
 {0.000179f, 0.685696f}, {0.000888f, 0.536508f}, {0.471f, 3.264f}, {0.012809f, 0.703171f},
 {0.218f, 1.046f}, {-0.094876f, 0.187459f}, {1.5e-05f, 0.442057f}, {0.001272f, 0.40803f},
 {0.222f, 1.042f}, {-0.115772f, 0.162604f}, {1.6e-05f, 0.444362f}, {0.001374f, 0.40243f},
 {0.227f, 0.996f}, {-0.117188f, 0.098323f}, {3e-05f, 0.531903f}, {0.001122f, 0.369589f},
 {0.228f, 0.99f}, {-0.12243f, 0.098658f}, {2.8e-05f, 0.530092f}, {0.001118f, 0.370399f}
};

__global__ void k_zero(float* p, int n){
  int i = blockIdx.x*blockDim.x + threadIdx.x;
  if (i < n) p[i] = 0.f;
}

// ---------------- luma ----------------
__global__ __launch_bounds__(256) void k_luma(const float* __restrict__ x, float* __restrict__ y, int n0, int nb){
  long long idx = (long long)blockIdx.x*blockDim.x + threadIdx.x;
  long long tot = (long long)nb*(FHW/4);
  if (idx >= tot) return;
  int n = (int)(idx / (FHW/4));
  int p = (int)(idx - (long long)n*(FHW/4));
  const float4* base = (const float4*)(x + (long long)(n0+n)*3*FHW);
  float4 r = base[p];
  float4 g = base[p + FHW/4];
  float4 b = base[p + 2*(FHW/4)];
  float4 o;
  o.x = 255.0f*(0.299f*r.x + 0.587f*g.x + 0.114f*b.x);
  o.y = 255.0f*(0.299f*r.y + 0.587f*g.y + 0.114f*b.y);
  o.z = 255.0f*(0.299f*r.z + 0.587f*g.z + 0.114f*b.z);
  o.w = 255.0f*(0.299f*r.w + 0.587f*g.w + 0.114f*b.w);
  ((float4*)(y + (long long)n*FHW))[p] = o;
}

// ------------- fused gaussian-normalize + NSS stats -------------
// per 32x32 tile: stage y (40x40 halo-4), separable conv -> xn on 34x34 (tile+ring),
// accumulate 22 stats; border-wrap pixels (i==0 | i==Hi-1 | j==0) skipped (fixup covers).
__global__ __launch_bounds__(256) void k_fused(const float* __restrict__ src, float* __restrict__ acc,
                                               int Hi, int Wi, int accBase, GW gw){
  __shared__ float ly[40][48];
  __shared__ float hs[40][36];
  __shared__ float h2[40][36];
  __shared__ float xs[34][36];
  __shared__ float wsum[4][22];
  int n = blockIdx.z;
  const float* im = src + (long long)n*Hi*Wi;
  int bx = blockIdx.x*32, by = blockIdx.y*32;
  int tid = threadIdx.x;
  bool fast = (bx >= 4) && (bx+36 <= Wi) && (by >= 4) && (by+36 <= Hi);
  if (fast){
    const float* base = im + (long long)(by-4)*Wi + (bx-4);
    for (int t = tid; t < 400; t += 256){
      int r = t/10, q = t-10*r;
      float4 v = *(const float4*)(base + (long long)r*Wi + 4*q);
      *(float4*)&ly[r][4*q] = v;
    }
  } else {
    for (int t = tid; t < 1600; t += 256){
      int r = t/40, c = t-40*r;
      int gi = by-4+r, gj = bx-4+c;
      float v = 0.f;
      if (gi>=0 && gi<Hi && gj>=0 && gj<Wi) v = im[(long long)gi*Wi+gj];
      ly[r][c] = v;
    }
  }
  __syncthreads();
  // horizontal pass: hs/h2[r][cg], r in [0,40), cg in [0,34); strip of 4 per thread
  for (int t = tid; t < 360; t += 256){
    int r = t/9, g = t-9*r; int c0 = 4*g;
    float v[10];
    #pragma unroll
    for (int k=0;k<10;k++) v[k] = ly[r][c0+k];
    #pragma unroll
    for (int q=0;q<4;q++){
      int cg = c0+q;
      if (cg < 34){
        float s=0.f, s2=0.f;
        #pragma unroll
        for (int k=0;k<7;k++){ float yv=v[q+k]; s += gw.w[k]*yv; s2 += gw.w[k]*yv*yv; }
        hs[r][cg]=s; h2[r][cg]=s2;
      }
    }
  }
  __syncthreads();
  // vertical pass + normalize: xs[rg][c], rg in [0,34), c in [0,34); strip of 4 rows
  for (int t = tid; t < 306; t += 256){
    int rg0 = t/34, c = t-34*rg0; int r0 = 4*rg0;
    float a[10], b[10];
    #pragma unroll
    for (int k=0;k<10;k++){
      int rr = r0+k;
      if (rr < 40){ a[k]=hs[rr][c]; b[k]=h2[rr][c]; } else { a[k]=0.f; b[k]=0.f; }
    }
    #pragma unroll
    for (int q=0;q<4;q++){
      int rg = r0+q;
      if (rg < 34){
        float mu=0.f, m2=0.f;
        #pragma unroll
        for (int k=0;k<7;k++){ mu += gw.w[k]*a[q+k]; m2 += gw.w[k]*b[q+k]; }
        float yv = ly[rg+3][c+3];
        float sig = sqrtf(fabsf(m2-mu*mu)+1e-8f);
        xs[rg][c] = (yv-mu)/(sig+1.f);
      }
    }
  }
  __syncthreads();
  // products + GGD sums over 32x32 tile (4 rows per thread, sliding window)
  float aR[22];
  #pragma unroll
  for (int k=0;k<22;k++) aR[k]=0.f;
  {
    int pc = tid & 31, rg = tid >> 5;
    int r0 = 4*rg;
    float xL[6], xC[6];
    #pragma unroll
    for (int k=0;k<6;k++){ xL[k]=xs[r0+k][pc]; xC[k]=xs[r0+k][pc+1]; }
    int j = bx+pc;
    #pragma unroll
    for (int q=0;q<4;q++){
      int i = by + r0 + q;
      if (i < Hi && j < Wi){
        float xc = xC[q+1];
        aR[0] += xc*xc; aR[1] += fabsf(xc);
        if (i != 0 && i != Hi-1 && j != 0){
          float pr4[4] = { xc*xL[q+1], xc*xC[q], xc*xL[q], xc*xL[q+2] };
          #pragma unroll
          for (int k=0;k<4;k++){
            float pp = pr4[k]; float qq = pp*pp;
            if (pp<0.f){ aR[2+5*k]+=1.f; aR[4+5*k]+=qq; }
            else if (pp>0.f){ aR[3+5*k]+=1.f; aR[5+5*k]+=qq; }
            aR[6+5*k]+=fabsf(pp);
          }
        }
      }
    }
  }
  int lane = tid & 63, wv = tid >> 6;
  #pragma unroll
  for (int k=0;k<22;k++){
    float v = aR[k];
    for (int off=32; off>0; off>>=1) v += __shfl_down(v, off, 64);
    if (lane==0) wsum[wv][k]=v;
  }
  __syncthreads();
  if (tid < 22){
    float s = wsum[0][tid]+wsum[1][tid]+wsum[2][tid]+wsum[3][tid];
    int slot = (blockIdx.x + blockIdx.y) & (NSLOT-1);
    atomicAdd(&acc[(((long long)(accBase + n))*NSLOT + slot)*22 + tid], s);
  }
}

// ------------- border xn strips: rows {0,1,Hi-2,Hi-1} and cols {0, Wi-1} -------------
__device__ float xn_at(const float* __restrict__ im, int Hi, int Wi, int i, int j, const GW& gw){
  float mu=0.f, m2=0.f;
  for (int kr=-3;kr<=3;kr++){
    int ii=i+kr; if (ii<0||ii>=Hi) continue;
    float wr = gw.w[kr+3];
    const float* row = im + (long long)ii*Wi;
    for (int kc=-3;kc<=3;kc++){
      int jj=j+kc; if (jj<0||jj>=Wi) continue;
      float w = wr*gw.w[kc+3];
      float yv = row[jj];
      mu += w*yv; m2 += w*yv*yv;
    }
  }
  float yv = im[(long long)i*Wi+j];
  float sig = sqrtf(fabsf(m2-mu*mu)+1e-8f);
  return (yv-mu)/(sig+1.f);
}

__global__ __launch_bounds__(256) void k_strips(const float* __restrict__ src, float* __restrict__ strip,
                                                int Hi, int Wi, GW gw){
  int n = blockIdx.y;
  const float* im = src + (long long)n*Hi*Wi;
  int C = 4*Wi + 2*Hi;
  float* sb = strip + (long long)n*C;
  for (int u = blockIdx.x*256 + threadIdx.x; u < C; u += gridDim.x*256){
    int i, j;
    if (u < 4*Wi){ int r=u/Wi; j=u-r*Wi; i = (r==0)?0:(r==1)?1:(r==2)?(Hi-2):(Hi-1); }
    else { int v=u-4*Wi; int c=v/Hi; i=v-c*Hi; j = c?(Wi-1):0; }
    sb[u] = xn_at(im, Hi, Wi, i, j, gw);
  }
}

__device__ float strip_get(const float* __restrict__ sb, int Hi, int Wi, int i, int j){
  if (i==0)    return sb[j];
  if (i==1)    return sb[Wi+j];
  if (i==Hi-2) return sb[2*Wi+j];
  if (i==Hi-1) return sb[3*Wi+j];
  if (j==0)    return sb[4*Wi+i];
  return sb[4*Wi+Hi+i];  // j==Wi-1
}

__global__ __launch_bounds__(256) void k_fixup(const float* __restrict__ strip, float* __restrict__ acc,
                                               int Hi, int Wi, int accBase){
  int n = blockIdx.y;
  int C = 4*Wi + 2*Hi;
  const float* sb = strip + (long long)n*C;
  int nB = 2*Wi + Hi - 2;
  float aR[20];
  #pragma unroll
  for (int k=0;k<20;k++) aR[k]=0.f;
  for (int u = blockIdx.x*256 + threadIdx.x; u < nB; u += gridDim.x*256){
    int i, j;
    if (u < Wi){ i=0; j=u; }
    else if (u < 2*Wi){ i=Hi-1; j=u-Wi; }
    else { i = u-2*Wi+1; j=0; }
    int jm = (j==0)?(Wi-1):(j-1);
    int im_ = (i==0)?(Hi-1):(i-1);
    int ip = (i==Hi-1)?0:(i+1);
    float xc  = strip_get(sb,Hi,Wi,i,j);
    float xl  = strip_get(sb,Hi,Wi,i,jm);
    float xu  = strip_get(sb,Hi,Wi,im_,j);
    float xul = strip_get(sb,Hi,Wi,im_,jm);
    float xdl = strip_get(sb,Hi,Wi,ip,jm);
    float pr4[4] = { xc*xl, xc*xu, xc*xul, xc*xdl };
    #pragma unroll
    for (int k=0;k<4;k++){
      float pp = pr4[k]; float qq = pp*pp;
      if (pp<0.f){ aR[0+5*k]+=1.f; aR[2+5*k]+=qq; }
      else if (pp>0.f){ aR[1+5*k]+=1.f; aR[3+5*k]+=qq; }
      aR[4+5*k]+=fabsf(pp);
    }
  }
  __shared__ float wsum[4][20];
  int lane = threadIdx.x & 63, wv = threadIdx.x >> 6;
  #pragma unroll
  for (int k=0;k<20;k++){
    float v = aR[k];
    for (int off=32; off>0; off>>=1) v += __shfl_down(v, off, 64);
    if (lane==0) wsum[wv][k]=v;
  }
  __syncthreads();
  if (threadIdx.x < 20){
    float s = wsum[0][threadIdx.x]+wsum[1][threadIdx.x]+wsum[2][threadIdx.x]+wsum[3][threadIdx.x];
    int slot = blockIdx.x & (NSLOT-1);
    atomicAdd(&acc[(((long long)(accBase + n))*NSLOT + slot)*22 + 2 + threadIdx.x], s);
  }
}

// ------------- bicubic half-resize -------------
__device__ double d_cubic(double x){
  double ax = fabs(x), ax2 = ax*ax, ax3 = ax2*ax;
  if (ax <= 1.0) return 1.5*ax3 - 2.5*ax2 + 1.0;
  if (ax <= 2.0) return -0.5*ax3 + 2.5*ax2 - 4.0*ax + 2.0;
  return 0.0;
}

__global__ void k_rsetup(float* __restrict__ wH, int* __restrict__ iH,
                         float* __restrict__ wW, int* __restrict__ iW){
  int t = blockIdx.x*blockDim.x + threadIdx.x;
  int inl, o; float* wp; int* ip;
  if (t < HHh){ inl = FH; wp = wH; ip = iH; o = t; }
  else if (t < HHh + HWw){ inl = FW; wp = wW; ip = iW; o = t - HHh; }
  else return;
  double u = 2.0*(o+1) - 0.5;
  double left = floor(u - 4.0);
  double wv[10]; int idx[10]; double s = 0.0;
  for (int p = 0; p < 10; p++){
    double ind = left + p;
    double xv = (u - ind)*0.5;
    double w = 0.5*d_cubic(xv);
    wv[p] = w; s += w;
    long long L2 = 2*(long long)inl;
    long long m = (long long)ind - 1;
    m = ((m % L2) + L2) % L2;
    idx[p] = (m < inl) ? (int)m : (int)(L2 - 1 - m);
  }
  for (int p = 0; p < 10; p++){
    wp[o*10+p] = (float)(wv[p]/s);
    ip[o*10+p] = idx[p];
  }
}

__global__ __launch_bounds__(256) void k_resizeh(const float* __restrict__ y, float* __restrict__ tmp,
                                                 const float* __restrict__ wH, const int* __restrict__ iH, int nb){
  int t = blockIdx.x*blockDim.x + threadIdx.x;
  int tot = nb*HHh*(FW/4);
  if (t >= tot) return;
  int j = t % (FW/4);
  int o = (t / (FW/4)) % HHh;
  int n = t / (HHh*(FW/4));
  const float* yi = y + (long long)n*FHW;
  float4 s = {0.f,0.f,0.f,0.f};
  for (int p = 0; p < 10; p++){
    float w = wH[o*10+p];
    int r = iH[o*10+p];
    float4 v = ((const float4*)(yi + (long long)r*FW))[j];
    s.x += w*v.x; s.y += w*v.y; s.z += w*v.z; s.w += w*v.w;
  }
  ((float4*)(tmp + (long long)n*TMPW))[o*(FW/4)+j] = s;
}

__global__ __launch_bounds__(256) void k_resizew(const float* __restrict__ tmp, float* __restrict__ yh,
                                                 const float* __restrict__ wW, const int* __restrict__ iW, int nb){
  int t = blockIdx.x*blockDim.x + threadIdx.x;
  int tot = nb*HHW;
  if (t >= tot) return;
  int q = t % HWw;
  int o = (t / HWw) % HHh;
  int n = t / HHW;
  const float* row = tmp + (long long)n*TMPW + (long long)o*FW;
  float s = 0.f;
  for (int p = 0; p < 10; p++) s += wW[q*10+p]*row[iW[q*10+p]];
  yh[(long long)n*HHW + (long long)o*HWw + q] = s;
}

// ------------- gamma ratio table -------------
__global__ void k_rtab(float* __restrict__ rt){
  int i = blockIdx.x*blockDim.x + threadIdx.x;
  if (i >= NG) return;
  float g = (float)(0.2 + 0.001*(double)i);
  double gd = (double)g;
  double r = exp(2.0*lgamma(2.0/gd) - lgamma(1.0/gd) - lgamma(3.0/gd));
  rt[i] = (float)r;
}

// ------------- features + argmin + SVR -------------
__global__ __launch_bounds__(256) void k_final(const float* __restrict__ acc, const float* __restrict__ rt,
                                               const float* __restrict__ sv, const float* __restrict__ coef,
                                               float* __restrict__ out){
  int n = blockIdx.x;
  __shared__ float A[44];
  __shared__ float targ[10];
  __shared__ float sfs[36];
  __shared__ int argi[10];
  __shared__ float slv[8], srv[8], feat[36];
  __shared__ float rbv[4]; __shared__ int rbi[4];
  __shared__ float ws2[4];
  int tid = threadIdx.x;
  if (tid < 44){
    int s = tid/22, k = tid-22*s;
    const float* p = acc + (((long long)(s*NIMG + n))*NSLOT)*22 + k;
    float sum = 0.f;
    for (int sl = 0; sl < NSLOT; sl++) sum += p[sl*22];
    A[tid] = sum;
  }
  __syncthreads();
  if (tid == 0){
    for (int s = 0; s < 2; s++){
      const float* Ap = A + s*22;
      double HWs = s ? (double)HHW : (double)FHW;
      double s2m = Ap[0]/HWs;
      double Em  = Ap[1]/HWs;
      targ[s*5+0] = (float)(s2m/(Em*Em));
      feat[s*18+1] = (float)s2m;
      for (int k = 0; k < 4; k++){
        double cl = Ap[2+5*k], cr = Ap[3+5*k], sl2 = Ap[4+5*k], sr2 = Ap[5+5*k], sab = Ap[6+5*k];
        double sl = sqrt(sl2/cl), sr = sqrt(sr2/cr);
        double gh = sl/sr;
        double rhat = (sab/HWs)*(sab/HWs)/((sl2+sr2)/HWs);
        double rhn = rhat*(gh*gh*gh + 1.0)*(gh + 1.0)/((gh*gh + 1.0)*(gh*gh + 1.0));
        targ[s*5+1+k] = (float)rhn;
        slv[s*4+k] = (float)sl; srv[s*4+k] = (float)sr;
        feat[s*18+2+4*k+2] = (float)(sl2/cl);
        feat[s*18+2+4*k+3] = (float)(sr2/cr);
      }
    }
  }
  __syncthreads();
  for (int tix = 0; tix < 10; tix++){
    float tv = targ[tix];
    float bv = 3.4e38f; int bi = 0;
    for (int i = tid; i < NG; i += 256){
      float d = fabsf(tv - rt[i]);
      if (d < bv){ bv = d; bi = i; }
    }
    for (int off = 32; off > 0; off >>= 1){
      float ov = __shfl_down(bv, off, 64);
      int   oi = __shfl_down(bi, off, 64);
      if (ov < bv || (ov == bv && oi < bi)){ bv = ov; bi = oi; }
    }
    int lane = tid & 63, wv = tid >> 6;
    if (lane == 0){ rbv[wv] = bv; rbi[wv] = bi; }
    __syncthreads();
    if (tid == 0){
      for (int w = 1; w < 4; w++)
        if (rbv[w] < bv || (rbv[w] == bv && rbi[w] < bi)){ bv = rbv[w]; bi = rbi[w]; }
      argi[tix] = bi;
    }
    __syncthreads();
  }
  if (tid == 0){
    for (int s = 0; s < 2; s++){
      feat[s*18+0] = (float)(0.2 + 0.001*(double)argi[s*5]);
      for (int k = 0; k < 4; k++){
        double a = 0.2 + 0.001*(double)argi[s*5+1+k];
        double e = exp(lgamma(2.0/a) - 0.5*(lgamma(1.0/a) + lgamma(3.0/a)));
        feat[s*18+2+4*k+0] = (float)a;
        feat[s*18+2+4*k+1] = (float)(((double)srv[s*4+k] - (double)slv[s*4+k])*e);
      }
    }
    for (int i = 0; i < 36; i++){
      float lo = FR[i][0], hi = FR[i][1];
      sfs[i] = -1.0f + 2.0f*(feat[i]-lo)/(hi-lo);
    }
  }
  __syncthreads();
  float local = 0.f;
  for (int v = tid; v < 600; v += 256){
    float d = 0.f;
    #pragma unroll 4
    for (int i = 0; i < 36; i++){ float df = sfs[i] - sv[v*36+i]; d += df*df; }
    local += expf(-0.05f*d)*coef[v];
  }
  for (int off = 32; off > 0; off >>= 1) local += __shfl_down(local, off, 64);
  int lane = tid & 63, wv = tid >> 6;
  if (lane == 0) ws2[wv] = local;
  __syncthreads();
  if (tid == 0) out[n] = ws2[0]+ws2[1]+ws2[2]+ws2[3] + 153.591f;
}

extern "C" void kernel_launch(void* const* d_in, const int* in_sizes, int n_in,
                              void* d_out, int out_size, void* d_ws, size_t ws_size,
                              hipStream_t stream){
  const float* x    = (const float*)d_in[0];
  const float* sv   = (const float*)d_in[1];
  const float* coef = (const float*)d_in[2];
  float* out = (float*)d_out;
  char* ws = (char*)d_ws;

  // workspace layout
  float* acc    = (float*)(ws + 0);        // 2*16*32*22 = 22528 floats
  float* rt     = (float*)(ws + 98304);    // 9801 floats
  float* wH     = (float*)(ws + 139264);   // 5400 floats
  int*   iH     = (int*)  (ws + 163840);
  float* wW     = (float*)(ws + 188416);   // 9600 floats
  int*   iW     = (int*)  (ws + 229376);
  float* stripF = (float*)(ws + 270336);   // NIMG * (4*FW+2*FH) = 16*9840 floats
  float* stripH = (float*)(ws + 901120);   // NIMG * (4*HWw+2*HHh) = 16*4920 floats
  float* big    = (float*)(ws + 1310720);

  size_t bigbytes = (ws_size > 1310720) ? ws_size - 1310720 : 0;
  size_t perimg = (size_t)(FHW + TMPW + HHW)*4;
  int nbmax = (int)(bigbytes / perimg);
  if (nbmax < 1) nbmax = 1;
  if (nbmax > NIMG) nbmax = NIMG;
  float* Ybuf = big;
  float* Tbuf = Ybuf + (size_t)nbmax*FHW;
  float* Hbuf = Tbuf + (size_t)nbmax*TMPW;

  GW gw;
  {
    double g[7], s = 0.0;
    for (int k = 0; k < 7; k++){ double d = k - 3; g[k] = exp(-d*d/(2.0*(7.0/6.0)*(7.0/6.0))); s += g[k]; }
    for (int k = 0; k < 7; k++) gw.w[k] = (float)(g[k]/s);
  }

  k_zero<<<(22528+255)/256, 256, 0, stream>>>(acc, 22528);
  k_rtab<<<(NG+255)/256, 256, 0, stream>>>(rt);
  k_rsetup<<<(HHh+HWw+255)/256, 256, 0, stream>>>(wH, iH, wW, iW);

  for (int n0 = 0; n0 < NIMG; n0 += nbmax){
    int nb = (NIMG - n0 < nbmax) ? (NIMG - n0) : nbmax;
    // 1. luma
    {
      long long tot = (long long)nb*(FHW/4);
      k_luma<<<(int)((tot+255)/256), 256, 0, stream>>>(x, Ybuf, n0, nb);
    }
    // 2. fused gnorm+NSS, full scale
    {
      dim3 g2((FW+31)/32, (FH+31)/32, nb);
      k_fused<<<g2, 256, 0, stream>>>(Ybuf, acc, FH, FW, 0*NIMG + n0, gw);
    }
    // 3. border strips + fixup, full scale
    {
      int C = 4*FW + 2*FH;
      k_strips<<<dim3((C+255)/256, nb), 256, 0, stream>>>(Ybuf, stripF, FH, FW, gw);
      int nB = 2*FW + FH - 2;
      k_fixup<<<dim3((nB+255)/256, nb), 256, 0, stream>>>(stripF, acc, FH, FW, 0*NIMG + n0);
    }
    // 4. resize H then W
    {
      int tot = nb*HHh*(FW/4);
      k_resizeh<<<(tot+255)/256, 256, 0, stream>>>(Ybuf, Tbuf, wH, iH, nb);
    }
    {
      int tot = nb*HHW;
      k_resizew<<<(tot+255)/256, 256, 0, stream>>>(Tbuf, Hbuf, wW, iW, nb);
    }
    // 5. fused gnorm+NSS, half scale
    {
      dim3 g2((HWw+31)/32, (HHh+31)/32, nb);
      k_fused<<<g2, 256, 0, stream>>>(Hbuf, acc, HHh, HWw, 1*NIMG + n0, gw);
    }
    // 6. border strips + fixup, half scale
    {
      int C = 4*HWw + 2*HHh;
      k_strips<<<dim3((C+255)/256, nb), 256, 0, stream>>>(Hbuf, stripH, HHh, HWw, gw);
      int nB = 2*HWw + HHh - 2;
      k_fixup<<<dim3((nB+255)/256, nb), 256, 0, stream>>>(stripH, acc, HHh, HWw, 1*NIMG + n0);
    }
  }

  k_final<<<NIMG, 256, 0, stream>>>(acc, rt, sv, coef, out);
}